// Round 7
// baseline (267.042 us; speedup 1.0000x reference)
//
#include <hip/hip_runtime.h>

// CapsuleLayer dynamic routing, MI355X. R10: barrier-free register votes.
//  - R9 votes_kernel (58us) still paid one stage->vmcnt0->barrier per 64KB
//    of output. R10 deletes LDS entirely: thread t <-> output column o=t,
//    W[i][:][t] is a coalesced per-thread column held in VGPRs (w[4][16]).
//    No __syncthreads, no LDS, no drain. 512 blocks x 512 thr, 2 blocks/CU.
//  - Round-0 fused into the producer: facc += V over the block's IC=4 i's
//    -> partialR0[512][32][512] (33.5MB). Deletes reduce0's 134MB votes
//    re-read (~22us) for +17MB of partial writes.
//  - votes layout [b][i][o]: each route block streams one contiguous 64KB
//    window instead of 64KB-strided rows.
//  - Routes/reduces keep R9's proven zero-barrier streaming form.
//
// route lane layout: lane owns o=[8l,8l+8); d=l>>1, h=l&1; h-combine
// shfl_xor(1); softmax over 32 d's shfl_xor {2,4,8,16,32}.
// Round-2 logits fold: logits2 = votes.(act0+act1).

#define B_  32
#define I_  2048
#define K_  16
#define O_  512
#define IC_ 4     // i's per votes-block
#define NGV 512   // votes blocks = I_/IC_
#define NGR 256   // route partial slices

// ---------------------------------------------------------------- votes ----
// grid 512: block g covers i = [g*4, g*4+4). thread t <-> o=t.
// w[ii][k] in VGPRs (64 regs, coalesced 2KB-row loads). x rows are
// block-uniform -> s_load. Zero LDS, zero barriers.
__global__ __launch_bounds__(512)
void votes_kernel(const float* __restrict__ x, const float* __restrict__ W,
                  float* __restrict__ votes, float* __restrict__ pr0)
{
    const int t  = threadIdx.x;             // o
    const int g  = blockIdx.x;              // 0..511
    const int i0 = g * IC_;

    // W columns into VGPRs: w[ii][k] = W[i0+ii][k][t]
    float w[IC_][K_];
    #pragma unroll
    for (int ii = 0; ii < IC_; ++ii)
        #pragma unroll
        for (int k = 0; k < K_; ++k)
            w[ii][k] = W[((size_t)(i0 + ii) * K_ + k) * O_ + t];

    #pragma unroll 2
    for (int b = 0; b < B_; ++b) {
        // x[b][i0..i0+4][0..16) = 64 consecutive floats, block-uniform -> SGPR
        float xs[IC_][K_];
        {
            const float4* xp = (const float4*)(x + ((size_t)b * I_ + i0) * K_);
            #pragma unroll
            for (int q = 0; q < 16; ++q) {
                const float4 v = xp[q];
                xs[q >> 2][4*(q & 3) + 0] = v.x;
                xs[q >> 2][4*(q & 3) + 1] = v.y;
                xs[q >> 2][4*(q & 3) + 2] = v.z;
                xs[q >> 2][4*(q & 3) + 3] = v.w;
            }
        }
        float facc = 0.f;
        #pragma unroll
        for (int ii = 0; ii < IC_; ++ii) {
            float V = 0.f;
            #pragma unroll
            for (int k = 0; k < K_; ++k) V = fmaf(xs[ii][k], w[ii][k], V);
            votes[((size_t)b * I_ + i0 + ii) * O_ + t] = V;   // [b][i][o]
            facc += V;
        }
        pr0[((size_t)g * B_ + b) * O_ + t] = facc;            // [g][b][o]
    }
}

// ---------------------------------------------------------------- route ----
// rounds 1/2: grid 2048 = 64 ichunks x 32 b; 256 thr = 4 waves x 8 i.
// Zero barriers, zero LDS. PASS=1: as_=act0; PASS=2: as_=act0+act1.
template<int PASS>
__global__ __launch_bounds__(256)
void route_kernel(const float* __restrict__ votes, const float* __restrict__ act0,
                  const float* __restrict__ act1, float* __restrict__ partial)
{
    const int tid  = threadIdx.x;
    const int lane = tid & 63;
    const int wave = tid >> 6;              // 0..3
    const int b    = blockIdx.x & 31;
    const int ic   = blockIdx.x >> 5;       // 0..63
    const int i0   = ic * 32 + wave * 8;

    float as_[8];
    {
        const float4* p = (const float4*)(act0 + b * O_ + lane * 8);
        float4 f0 = p[0], f1 = p[1];
        as_[0]=f0.x; as_[1]=f0.y; as_[2]=f0.z; as_[3]=f0.w;
        as_[4]=f1.x; as_[5]=f1.y; as_[6]=f1.z; as_[7]=f1.w;
        if (PASS == 2) {
            const float4* q = (const float4*)(act1 + b * O_ + lane * 8);
            float4 g0 = q[0], g1 = q[1];
            as_[0]+=g0.x; as_[1]+=g0.y; as_[2]+=g0.z; as_[3]+=g0.w;
            as_[4]+=g1.x; as_[5]+=g1.y; as_[6]+=g1.z; as_[7]+=g1.w;
        }
    }

    float facc[8];
    #pragma unroll
    for (int j = 0; j < 8; ++j) facc[j] = 0.f;

    #pragma unroll
    for (int ii = 0; ii < 8; ++ii) {
        const float4* vp = (const float4*)(votes + ((size_t)b * I_ + i0 + ii) * O_ + lane * 8);
        const float4 v0 = vp[0], v1 = vp[1];
        const float V[8] = {v0.x, v0.y, v0.z, v0.w, v1.x, v1.y, v1.z, v1.w};
        float p0 = 0.f;
        #pragma unroll
        for (int j = 0; j < 8; ++j) p0 = fmaf(V[j], as_[j], p0);
        p0 += __shfl_xor(p0, 1);            // combine the two a-halves
        // softmax over 32 d's (no max-sub: |logits| small, f32-safe)
        const float e = __expf(p0);
        float s = e;
        s += __shfl_xor(s, 2);
        s += __shfl_xor(s, 4);
        s += __shfl_xor(s, 8);
        s += __shfl_xor(s, 16);
        s += __shfl_xor(s, 32);
        const float r = e * __builtin_amdgcn_rcpf(s);
        #pragma unroll
        for (int j = 0; j < 8; ++j) facc[j] = fmaf(r, V[j], facc[j]);
    }

    float4* dst = (float4*)(partial + ((size_t)(ic * 4 + wave) * B_ + b) * O_ + lane * 8);
    dst[0] = make_float4(facc[0], facc[1], facc[2], facc[3]);
    dst[1] = make_float4(facc[4], facc[5], facc[6], facc[7]);
}

// --------------------------------------------------------------- reduce ----
// sum nw partials ([nw][B][O] as float4 columns) -> *scale + bias -> squash
// over A -> out. grid 512 x 256: block covers 8 float4-columns, 32 w-slices.
__global__ __launch_bounds__(256)
void reduce_squash(const float* __restrict__ partial, const float* __restrict__ bias,
                   float scale, int nw, float* __restrict__ out)
{
    const int t   = threadIdx.x;
    const int g4  = blockIdx.x * 8 + (t & 7);    // float4 column, 0..4095
    const int sl  = t >> 3;                      // w-slice 0..31
    const int per = nw >> 5;                     // nw/32
    const float4* p4 = (const float4*)partial;
    float4 s = make_float4(0.f, 0.f, 0.f, 0.f);
    #pragma unroll 8
    for (int w = sl * per; w < sl * per + per; ++w) {
        const float4 v = p4[(size_t)w * (B_ * O_ / 4) + g4];
        s.x += v.x; s.y += v.y; s.z += v.z; s.w += v.w;
    }
    __shared__ float4 red[256];
    red[t] = s;
    __syncthreads();
    if (t < 8) {
        float4 v = red[t];
        #pragma unroll
        for (int r = 1; r < 32; ++r) {
            const float4 u = red[t + 8 * r];
            v.x += u.x; v.y += u.y; v.z += u.z; v.w += u.w;
        }
        const float4 bi = ((const float4*)bias)[g4 & 127];
        float4 p;
        p.x = fmaf(v.x, scale, bi.x);
        p.y = fmaf(v.y, scale, bi.y);
        p.z = fmaf(v.z, scale, bi.z);
        p.w = fmaf(v.w, scale, bi.w);
        float nn = p.x*p.x + p.y*p.y + p.z*p.z + p.w*p.w;
        nn += __shfl_xor(nn, 1);     // 4 threads (16 a's) share one d
        nn += __shfl_xor(nn, 2);
        const float sc = sqrtf(nn) / (1.f + nn);
        p.x *= sc; p.y *= sc; p.z *= sc; p.w *= sc;
        ((float4*)out)[g4] = p;
    }
}

extern "C" void kernel_launch(void* const* d_in, const int* in_sizes, int n_in,
                              void* d_out, int out_size, void* d_ws, size_t ws_size,
                              hipStream_t stream) {
    const float* x    = (const float*)d_in[0];   // [32,2048,16]
    const float* W    = (const float*)d_in[1];   // [2048,16,512]
    const float* bias = (const float*)d_in[2];   // [512]
    float* out = (float*)d_out;                  // [32,512]

    float* votes   = (float*)d_ws;                       // 32*2048*512 f32 = 134.2 MB
    float* pr0     = votes + (size_t)B_ * I_ * O_;       // 512*32*512 f32 = 33.5 MB
    float* partial = pr0 + (size_t)NGV * B_ * O_;        // 256*32*512 f32 = 16.8 MB
    float* act0    = partial + (size_t)NGR * B_ * O_;    // 64 KB
    float* act1    = act0 + B_ * O_;                     // 64 KB

    votes_kernel<<<NGV, 512, 0, stream>>>(x, W, votes, pr0);
    reduce_squash<<<512, 256, 0, stream>>>(pr0, bias, 1.f / 32.f, NGV, act0);
    route_kernel<1><<<2048, 256, 0, stream>>>(votes, act0, nullptr, partial);
    reduce_squash<<<512, 256, 0, stream>>>(partial, bias, 1.f, NGR, act1);
    route_kernel<2><<<2048, 256, 0, stream>>>(votes, act0, act1, partial);
    reduce_squash<<<512, 256, 0, stream>>>(partial, bias, 1.f, NGR, out);
}

// Round 8
// 212.824 us; speedup vs baseline: 1.2548x; 1.2548x over previous
//
#include <hip/hip_runtime.h>

// CapsuleLayer dynamic routing, MI355X. R11: float4 register-votes producer.
//  - R10's producer (113us) used scalar dword stores (1 float/thread) and a
//    serial per-b chain -> 1.5 TB/s writes. R11 remaps thread <-> o-quad:
//    thread owns o4 = 4*(t&127) and 8 b's (bq = t>>7, wave-uniform).
//    W columns load as float4 (w4[16], 64 VGPR, coalesced 2KB rows); votes
//    store as float4 (wave-contiguous 1KB). 4x wider on both sides.
//  - i outer (IC=4, 512 blocks x 512 thr, 2 blocks/CU = 16 waves/CU),
//    b inner unrolled 8 with wave-uniform s_load x. Live set ~110 VGPR
//    under the 128 cap from __launch_bounds__(512,4) -- margin, no spill.
//  - Round-0 fused: facc4[8b] += V4 over the block's 4 i's -> pr0[512][32][512]
//    (33.5MB), deleting the 134MB votes re-read in reduce0.
//  - votes layout [b][i][o]; routes/reduces unchanged from R10 (streaming,
//    zero barriers, zero LDS).
//
// route lane layout: lane owns o=[8l,8l+8); d=l>>1, h=l&1; h-combine
// shfl_xor(1); softmax over 32 d's shfl_xor {2,4,8,16,32}.
// Round-2 logits fold: logits2 = votes.(act0+act1).

#define B_  32
#define I_  2048
#define K_  16
#define O_  512
#define IC_ 4     // i's per votes-block
#define NGV 512   // votes blocks = I_/IC_
#define NGR 256   // route partial slices

// ---------------------------------------------------------------- votes ----
// grid 512: block g covers i = [g*4, g*4+4). thread t: o-quad oq = t&127,
// b-group bq = t>>7 (8 b's). Zero LDS, zero barriers, all-float4 traffic.
__global__ __launch_bounds__(512, 4)
void votes_kernel(const float* __restrict__ x, const float* __restrict__ W,
                  float* __restrict__ votes, float* __restrict__ pr0)
{
    const int t  = threadIdx.x;
    const int g  = blockIdx.x;              // 0..511
    const int i0 = g * IC_;
    const int oq = t & 127;                 // o-quad: o = 4*oq .. 4*oq+4
    const int bq = __builtin_amdgcn_readfirstlane(t >> 7);   // wave-uniform
    const int b0 = bq * 8;

    float4 facc[8];
    #pragma unroll
    for (int bb = 0; bb < 8; ++bb) facc[bb] = make_float4(0.f, 0.f, 0.f, 0.f);

    #pragma unroll 1
    for (int i = 0; i < IC_; ++i) {
        // W column-quad into VGPRs: w4[k] = W[i0+i][k][4oq..4oq+4)
        float4 w4[K_];
        {
            const float4* Wp = (const float4*)(W + (size_t)(i0 + i) * (K_ * O_)) + oq;
            #pragma unroll
            for (int k = 0; k < K_; ++k) w4[k] = Wp[k * (O_ / 4)];
        }
        #pragma unroll
        for (int bb = 0; bb < 8; ++bb) {
            const int b = b0 + bb;
            // x[b][i0+i][:] block/wave-uniform -> s_load
            const float4* xp = (const float4*)(x + ((size_t)b * I_ + i0 + i) * K_);
            const float4 x0 = xp[0], x1 = xp[1], x2 = xp[2], x3 = xp[3];
            const float xk[16] = {x0.x, x0.y, x0.z, x0.w, x1.x, x1.y, x1.z, x1.w,
                                  x2.x, x2.y, x2.z, x2.w, x3.x, x3.y, x3.z, x3.w};
            float4 V = make_float4(0.f, 0.f, 0.f, 0.f);
            #pragma unroll
            for (int k = 0; k < K_; ++k) {
                V.x = fmaf(xk[k], w4[k].x, V.x);
                V.y = fmaf(xk[k], w4[k].y, V.y);
                V.z = fmaf(xk[k], w4[k].z, V.z);
                V.w = fmaf(xk[k], w4[k].w, V.w);
            }
            // votes[b][i0+i][o4] -- wave-contiguous 1KB dwordx4 store
            ((float4*)(votes + ((size_t)b * I_ + i0 + i) * O_))[oq] = V;
            facc[bb].x += V.x; facc[bb].y += V.y;
            facc[bb].z += V.z; facc[bb].w += V.w;
        }
    }

    // pr0[g][b][o4]
    #pragma unroll
    for (int bb = 0; bb < 8; ++bb)
        ((float4*)(pr0 + ((size_t)g * B_ + b0 + bb) * O_))[oq] = facc[bb];
}

// ---------------------------------------------------------------- route ----
// rounds 1/2: grid 2048 = 64 ichunks x 32 b; 256 thr = 4 waves x 8 i.
// Zero barriers, zero LDS. PASS=1: as_=act0; PASS=2: as_=act0+act1.
template<int PASS>
__global__ __launch_bounds__(256)
void route_kernel(const float* __restrict__ votes, const float* __restrict__ act0,
                  const float* __restrict__ act1, float* __restrict__ partial)
{
    const int tid  = threadIdx.x;
    const int lane = tid & 63;
    const int wave = tid >> 6;              // 0..3
    const int b    = blockIdx.x & 31;
    const int ic   = blockIdx.x >> 5;       // 0..63
    const int i0   = ic * 32 + wave * 8;

    float as_[8];
    {
        const float4* p = (const float4*)(act0 + b * O_ + lane * 8);
        float4 f0 = p[0], f1 = p[1];
        as_[0]=f0.x; as_[1]=f0.y; as_[2]=f0.z; as_[3]=f0.w;
        as_[4]=f1.x; as_[5]=f1.y; as_[6]=f1.z; as_[7]=f1.w;
        if (PASS == 2) {
            const float4* q = (const float4*)(act1 + b * O_ + lane * 8);
            float4 g0 = q[0], g1 = q[1];
            as_[0]+=g0.x; as_[1]+=g0.y; as_[2]+=g0.z; as_[3]+=g0.w;
            as_[4]+=g1.x; as_[5]+=g1.y; as_[6]+=g1.z; as_[7]+=g1.w;
        }
    }

    float facc[8];
    #pragma unroll
    for (int j = 0; j < 8; ++j) facc[j] = 0.f;

    #pragma unroll
    for (int ii = 0; ii < 8; ++ii) {
        const float4* vp = (const float4*)(votes + ((size_t)b * I_ + i0 + ii) * O_ + lane * 8);
        const float4 v0 = vp[0], v1 = vp[1];
        const float V[8] = {v0.x, v0.y, v0.z, v0.w, v1.x, v1.y, v1.z, v1.w};
        float p0 = 0.f;
        #pragma unroll
        for (int j = 0; j < 8; ++j) p0 = fmaf(V[j], as_[j], p0);
        p0 += __shfl_xor(p0, 1);            // combine the two a-halves
        // softmax over 32 d's (no max-sub: |logits| small, f32-safe)
        const float e = __expf(p0);
        float s = e;
        s += __shfl_xor(s, 2);
        s += __shfl_xor(s, 4);
        s += __shfl_xor(s, 8);
        s += __shfl_xor(s, 16);
        s += __shfl_xor(s, 32);
        const float r = e * __builtin_amdgcn_rcpf(s);
        #pragma unroll
        for (int j = 0; j < 8; ++j) facc[j] = fmaf(r, V[j], facc[j]);
    }

    float4* dst = (float4*)(partial + ((size_t)(ic * 4 + wave) * B_ + b) * O_ + lane * 8);
    dst[0] = make_float4(facc[0], facc[1], facc[2], facc[3]);
    dst[1] = make_float4(facc[4], facc[5], facc[6], facc[7]);
}

// --------------------------------------------------------------- reduce ----
// sum nw partials ([nw][B][O] as float4 columns) -> *scale + bias -> squash
// over A -> out. grid 512 x 256: block covers 8 float4-columns, 32 w-slices.
__global__ __launch_bounds__(256)
void reduce_squash(const float* __restrict__ partial, const float* __restrict__ bias,
                   float scale, int nw, float* __restrict__ out)
{
    const int t   = threadIdx.x;
    const int g4  = blockIdx.x * 8 + (t & 7);    // float4 column, 0..4095
    const int sl  = t >> 3;                      // w-slice 0..31
    const int per = nw >> 5;                     // nw/32
    const float4* p4 = (const float4*)partial;
    float4 s = make_float4(0.f, 0.f, 0.f, 0.f);
    #pragma unroll 8
    for (int w = sl * per; w < sl * per + per; ++w) {
        const float4 v = p4[(size_t)w * (B_ * O_ / 4) + g4];
        s.x += v.x; s.y += v.y; s.z += v.z; s.w += v.w;
    }
    __shared__ float4 red[256];
    red[t] = s;
    __syncthreads();
    if (t < 8) {
        float4 v = red[t];
        #pragma unroll
        for (int r = 1; r < 32; ++r) {
            const float4 u = red[t + 8 * r];
            v.x += u.x; v.y += u.y; v.z += u.z; v.w += u.w;
        }
        const float4 bi = ((const float4*)bias)[g4 & 127];
        float4 p;
        p.x = fmaf(v.x, scale, bi.x);
        p.y = fmaf(v.y, scale, bi.y);
        p.z = fmaf(v.z, scale, bi.z);
        p.w = fmaf(v.w, scale, bi.w);
        float nn = p.x*p.x + p.y*p.y + p.z*p.z + p.w*p.w;
        nn += __shfl_xor(nn, 1);     // 4 threads (16 a's) share one d
        nn += __shfl_xor(nn, 2);
        const float sc = sqrtf(nn) / (1.f + nn);
        p.x *= sc; p.y *= sc; p.z *= sc; p.w *= sc;
        ((float4*)out)[g4] = p;
    }
}

extern "C" void kernel_launch(void* const* d_in, const int* in_sizes, int n_in,
                              void* d_out, int out_size, void* d_ws, size_t ws_size,
                              hipStream_t stream) {
    const float* x    = (const float*)d_in[0];   // [32,2048,16]
    const float* W    = (const float*)d_in[1];   // [2048,16,512]
    const float* bias = (const float*)d_in[2];   // [512]
    float* out = (float*)d_out;                  // [32,512]

    float* votes   = (float*)d_ws;                       // 32*2048*512 f32 = 134.2 MB
    float* pr0     = votes + (size_t)B_ * I_ * O_;       // 512*32*512 f32 = 33.5 MB
    float* partial = pr0 + (size_t)NGV * B_ * O_;        // 256*32*512 f32 = 16.8 MB
    float* act0    = partial + (size_t)NGR * B_ * O_;    // 64 KB
    float* act1    = act0 + B_ * O_;                     // 64 KB

    votes_kernel<<<NGV, 512, 0, stream>>>(x, W, votes, pr0);
    reduce_squash<<<512, 256, 0, stream>>>(pr0, bias, 1.f / 32.f, NGV, act0);
    route_kernel<1><<<2048, 256, 0, stream>>>(votes, act0, nullptr, partial);
    reduce_squash<<<512, 256, 0, stream>>>(partial, bias, 1.f, NGR, act1);
    route_kernel<2><<<2048, 256, 0, stream>>>(votes, act0, act1, partial);
    reduce_squash<<<512, 256, 0, stream>>>(partial, bias, 1.f, NGR, out);
}